// Round 7
// baseline (1096.602 us; speedup 1.0000x reference)
//
#include <hip/hip_runtime.h>
#include <math.h>

#define IN_C 128
#define OUT_C 128
#define BN_EPS 1e-5f

#define EPW 8            // edges per wave per iteration
#define WAVES 4          // waves per block
#define EPB (EPW*WAVES)  // 32 edges per block-iteration
#define NODES_PER_ITER 16

// float atomic max via int/uint monotonic-order trick (agg initialized to -inf)
__device__ __forceinline__ void atomicMaxFloat(float* addr, float val) {
    if (val >= 0.0f) {
        atomicMax((int*)addr, __float_as_int(val));
    } else {
        atomicMin((unsigned int*)addr, __float_as_uint(val));
    }
}

// ---------------- init: agg = -inf, stats = 0 ----------------
__global__ __launch_bounds__(256) void k_init(float* __restrict__ out, int n_elem,
                                              float* __restrict__ stats) {
    int idx = blockIdx.x * blockDim.x + threadIdx.x;
    int stride = gridDim.x * blockDim.x;
    for (int i = idx; i < n_elem; i += stride) out[i] = -INFINITY;
    if (blockIdx.x == 0 && threadIdx.x < 256) stats[threadIdx.x] = 0.0f;
}

// ---------------- node precompute: A = x@(W1t-W1b)+b1, B = x@W1b ----------------
__global__ __launch_bounds__(256) void k_node(const float* __restrict__ x,
                                              const float* __restrict__ W1,
                                              const float* __restrict__ b1,
                                              float* __restrict__ A,
                                              float* __restrict__ Bm,
                                              int n_nodes) {
    __shared__ float xs[NODES_PER_ITER][IN_C];
    int t = threadIdx.x;
    int c = t & 127;
    bool isA = (t < 128);             // waves 0,1 -> A; waves 2,3 -> B (wave-uniform)
    float bias = b1[c];
    for (int base = blockIdx.x * NODES_PER_ITER; base < n_nodes;
         base += gridDim.x * NODES_PER_ITER) {
        int nn = min(NODES_PER_ITER, n_nodes - base);
        __syncthreads();
        for (int i = t; i < nn * IN_C; i += 256) {
            int n = i >> 7, k = i & 127;
            xs[n][k] = x[(size_t)(base + n) * IN_C + k];
        }
        __syncthreads();
        float acc[NODES_PER_ITER];
#pragma unroll
        for (int n = 0; n < NODES_PER_ITER; n++) acc[n] = 0.0f;
        for (int kh = 0; kh < IN_C; kh += 4) {
            float w[4];
#pragma unroll
            for (int j = 0; j < 4; j++) {
                float wbot = W1[(size_t)(kh + j + 128) * OUT_C + c];
                w[j] = isA ? (W1[(size_t)(kh + j) * OUT_C + c] - wbot) : wbot;
            }
#pragma unroll
            for (int n = 0; n < NODES_PER_ITER; n++) {
                float4 xv = *(const float4*)&xs[n][kh];
                acc[n] = fmaf(xv.x, w[0], acc[n]);
                acc[n] = fmaf(xv.y, w[1], acc[n]);
                acc[n] = fmaf(xv.z, w[2], acc[n]);
                acc[n] = fmaf(xv.w, w[3], acc[n]);
            }
        }
        float* dst = isA ? A : Bm;
        float add = isA ? bias : 0.0f;
        for (int n = 0; n < nn; n++)
            dst[(size_t)(base + n) * OUT_C + c] = acc[n] + add;
    }
}

// ---------------- edge kernel: h = relu(A[i]+B[j])@W2 + b2 ; atomic max into agg ----------------
__global__ __launch_bounds__(256) void k_edge(const float* __restrict__ A,
                                              const float* __restrict__ Bm,
                                              const int* __restrict__ esrc,
                                              const int* __restrict__ edst,
                                              const float* __restrict__ W2,
                                              const float* __restrict__ b2,
                                              float* __restrict__ agg,
                                              int n_edges) {
    // W2 staged as [kh][c][j] = W2[(4kh+j)*128 + c]; a wave's b128 read of
    // w2s[kh][c][0] moves 1024B = the 8-cycle LDS BW floor (no conflicts).
    __shared__ float w2s[32][OUT_C][4];   // 64 KB
    __shared__ float rs[EPB][IN_C];       // 16 KB, per-wave private rows
    int t = threadIdx.x;
    int wave = t >> 6, lane = t & 63;
    for (int i = t; i < IN_C * OUT_C; i += 256) {
        int k = i >> 7, cc = i & 127;
        w2s[k >> 2][cc][k & 3] = W2[i];
    }
    int c1 = lane, c2 = lane + 64;
    float bias1 = b2[c1], bias2 = b2[c2];
    __syncthreads();   // only barrier needed: W2 staged cross-wave

    for (int gbase = blockIdx.x * EPB; gbase < n_edges; gbase += gridDim.x * EPB) {
        int ebase = gbase + wave * EPW;
        int dsts[EPW];
        // phase 1: r = relu(A[i]+B[j]) into this wave's private LDS rows
#pragma unroll
        for (int e = 0; e < EPW; e++) {
            int eid = ebase + e;
            int row = wave * EPW + e;
            if (eid < n_edges) {
                int j = esrc[eid];
                int i = edst[eid];
                dsts[e] = i;
                float2 av = *(const float2*)&A[(size_t)i * OUT_C + lane * 2];
                float2 bv = *(const float2*)&Bm[(size_t)j * OUT_C + lane * 2];
                float2 r;
                r.x = fmaxf(av.x + bv.x, 0.0f);
                r.y = fmaxf(av.y + bv.y, 0.0f);
                *(float2*)&rs[row][lane * 2] = r;
            } else {
                dsts[e] = -1;
            }
        }
        // no __syncthreads needed: each wave reads only rows it wrote
        // phase 2: per lane, channels c1 and c2 for EPW edges
        float acc1[EPW], acc2[EPW];
#pragma unroll
        for (int e = 0; e < EPW; e++) { acc1[e] = bias1; acc2[e] = bias2; }
        for (int kh = 0; kh < 32; kh++) {
            float4 w1v = *(const float4*)&w2s[kh][c1][0];
            float4 w2v = *(const float4*)&w2s[kh][c2][0];
#pragma unroll
            for (int e = 0; e < EPW; e++) {
                float4 rv = *(const float4*)&rs[wave * EPW + e][kh * 4];
                acc1[e] = fmaf(rv.x, w1v.x, acc1[e]);
                acc1[e] = fmaf(rv.y, w1v.y, acc1[e]);
                acc1[e] = fmaf(rv.z, w1v.z, acc1[e]);
                acc1[e] = fmaf(rv.w, w1v.w, acc1[e]);
                acc2[e] = fmaf(rv.x, w2v.x, acc2[e]);
                acc2[e] = fmaf(rv.y, w2v.y, acc2[e]);
                acc2[e] = fmaf(rv.z, w2v.z, acc2[e]);
                acc2[e] = fmaf(rv.w, w2v.w, acc2[e]);
            }
        }
#pragma unroll
        for (int e = 0; e < EPW; e++) {
            if (dsts[e] >= 0) {
                atomicMaxFloat(&agg[(size_t)dsts[e] * OUT_C + c1], acc1[e]);
                atomicMaxFloat(&agg[(size_t)dsts[e] * OUT_C + c2], acc2[e]);
            }
        }
    }
}

// ---------------- stats: fix -inf -> 0, accumulate sum/sumsq per channel ----------------
__global__ __launch_bounds__(256) void k_stats(float* __restrict__ agg, int n_nodes,
                                               float* __restrict__ gsum,
                                               float* __restrict__ gsumsq) {
    __shared__ float red[256];
    int t = threadIdx.x;
    int c = t & 127, h = t >> 7;
    float s = 0.0f, s2 = 0.0f;
    for (int row = blockIdx.x * 2 + h; row < n_nodes; row += gridDim.x * 2) {
        size_t idx = (size_t)row * OUT_C + c;
        float v = agg[idx];
        if (v == -INFINITY) { v = 0.0f; agg[idx] = 0.0f; }
        s += v;
        s2 += v * v;
    }
    red[t] = s;
    __syncthreads();
    if (h == 0) atomicAdd(&gsum[c], s + red[t + 128]);
    __syncthreads();
    red[t] = s2;
    __syncthreads();
    if (h == 0) atomicAdd(&gsumsq[c], s2 + red[t + 128]);
}

// ---------------- finalize: scale/shift from stats ----------------
__global__ __launch_bounds__(128) void k_finalize(const float* __restrict__ gsum,
                                                  const float* __restrict__ gsumsq,
                                                  const float* __restrict__ gamma,
                                                  const float* __restrict__ beta,
                                                  float* __restrict__ scale,
                                                  float* __restrict__ shift,
                                                  int n_nodes) {
    int c = threadIdx.x;
    if (c < OUT_C) {
        float inv_n = 1.0f / (float)n_nodes;
        float mean = gsum[c] * inv_n;
        float var = fmaxf(gsumsq[c] * inv_n - mean * mean, 0.0f);
        float sc = gamma[c] * rsqrtf(var + BN_EPS);
        scale[c] = sc;
        shift[c] = beta[c] - mean * sc;
    }
}

// ---------------- normalize in place ----------------
__global__ __launch_bounds__(256) void k_norm(float* __restrict__ out,
                                              const float* __restrict__ scale,
                                              const float* __restrict__ shift,
                                              int n_vec) {
    int idx = blockIdx.x * blockDim.x + threadIdx.x;
    int stride = gridDim.x * blockDim.x;
    for (int i = idx; i < n_vec; i += stride) {
        float4 v = ((const float4*)out)[i];
        int c = (i * 4) & 127;
        float4 sc = *(const float4*)&scale[c];
        float4 sh = *(const float4*)&shift[c];
        v.x = fmaf(v.x, sc.x, sh.x);
        v.y = fmaf(v.y, sc.y, sh.y);
        v.z = fmaf(v.z, sc.z, sh.z);
        v.w = fmaf(v.w, sc.w, sh.w);
        ((float4*)out)[i] = v;
    }
}

extern "C" void kernel_launch(void* const* d_in, const int* in_sizes, int n_in,
                              void* d_out, int out_size, void* d_ws, size_t ws_size,
                              hipStream_t stream) {
    const float* x     = (const float*)d_in[0];
    const int*   ei    = (const int*)d_in[1];
    const float* W1    = (const float*)d_in[2];
    const float* b1    = (const float*)d_in[3];
    const float* W2    = (const float*)d_in[4];
    const float* b2    = (const float*)d_in[5];
    const float* gamma = (const float*)d_in[6];
    const float* beta  = (const float*)d_in[7];

    int n_nodes = in_sizes[0] / IN_C;
    int n_edges = in_sizes[1] / 2;
    const int* esrc = ei;             // edge_index[0] = source j
    const int* edst = ei + n_edges;   // edge_index[1] = target i

    float* out = (float*)d_out;
    float* A   = (float*)d_ws;
    float* Bm  = A + (size_t)n_nodes * OUT_C;
    float* stats = Bm + (size_t)n_nodes * OUT_C;
    float* gsum   = stats;
    float* gsumsq = stats + 128;
    float* scale  = stats + 256;
    float* shift  = stats + 384;

    int n_elem = n_nodes * OUT_C;

    k_init<<<2048, 256, 0, stream>>>(out, n_elem, stats);
    k_node<<<2048, 256, 0, stream>>>(x, W1, b1, A, Bm, n_nodes);
    k_edge<<<2048, 256, 0, stream>>>(A, Bm, esrc, edst, W2, b2, out, n_edges);
    k_stats<<<1024, 256, 0, stream>>>(out, n_nodes, gsum, gsumsq);
    k_finalize<<<1, 128, 0, stream>>>(gsum, gsumsq, gamma, beta, scale, shift, n_nodes);
    k_norm<<<2048, 256, 0, stream>>>(out, scale, shift, n_elem / 4);
}

// Round 10
// 511.033 us; speedup vs baseline: 2.1459x; 2.1459x over previous
//
#include <hip/hip_runtime.h>
#include <hip/hip_fp16.h>
#include <math.h>

#define IN_C 128
#define OUT_C 128
#define BN_EPS 1e-5f
#define BIAS_OFF 256.0f

#define EPW 32            // edges per wave-iter (2 MFMA M-tiles of 16)
#define WAVES 4
#define EPB (EPW*WAVES)   // 128 edges per block-iter
#define RT_PITCH 136      // f16 per row: 128 + 8 pad (272B stride -> 2-way max)
#define NODES_PER_ITER 16

typedef __fp16 f16x8 __attribute__((ext_vector_type(8)));
typedef __fp16 f16x2 __attribute__((ext_vector_type(2)));
typedef float f32x4 __attribute__((ext_vector_type(4)));

// ---------------- init: agg = 0-bits (biased sentinel), stats = 0 ----------------
__global__ __launch_bounds__(256) void k_init(float* __restrict__ out, int n_elem,
                                              float* __restrict__ stats) {
    int idx = blockIdx.x * blockDim.x + threadIdx.x;
    int stride = gridDim.x * blockDim.x;
    for (int i = idx; i < n_elem; i += stride) out[i] = 0.0f;   // uint bits 0 == sentinel
    if (blockIdx.x == 0 && threadIdx.x < 256) stats[threadIdx.x] = 0.0f;
}

// ---------------- node precompute: A = x@(W1t-W1b)+b1, B = x@W1b (fp32) ----------------
__global__ __launch_bounds__(256) void k_node(const float* __restrict__ x,
                                              const float* __restrict__ W1,
                                              const float* __restrict__ b1,
                                              float* __restrict__ A,
                                              float* __restrict__ Bm,
                                              int n_nodes) {
    __shared__ float xs[NODES_PER_ITER][IN_C];
    int t = threadIdx.x;
    int c = t & 127;
    bool isA = (t < 128);
    float bias = b1[c];
    for (int base = blockIdx.x * NODES_PER_ITER; base < n_nodes;
         base += gridDim.x * NODES_PER_ITER) {
        int nn = min(NODES_PER_ITER, n_nodes - base);
        __syncthreads();
        for (int i = t; i < nn * IN_C; i += 256) {
            int n = i >> 7, k = i & 127;
            xs[n][k] = x[(size_t)(base + n) * IN_C + k];
        }
        __syncthreads();
        float acc[NODES_PER_ITER];
#pragma unroll
        for (int n = 0; n < NODES_PER_ITER; n++) acc[n] = 0.0f;
        for (int kh = 0; kh < IN_C; kh += 4) {
            float w[4];
#pragma unroll
            for (int j = 0; j < 4; j++) {
                float wbot = W1[(size_t)(kh + j + 128) * OUT_C + c];
                w[j] = isA ? (W1[(size_t)(kh + j) * OUT_C + c] - wbot) : wbot;
            }
#pragma unroll
            for (int n = 0; n < NODES_PER_ITER; n++) {
                float4 xv = *(const float4*)&xs[n][kh];
                acc[n] = fmaf(xv.x, w[0], acc[n]);
                acc[n] = fmaf(xv.y, w[1], acc[n]);
                acc[n] = fmaf(xv.z, w[2], acc[n]);
                acc[n] = fmaf(xv.w, w[3], acc[n]);
            }
        }
        float* dst = isA ? A : Bm;
        float add = isA ? bias : 0.0f;
        for (int n = 0; n < nn; n++)
            dst[(size_t)(base + n) * OUT_C + c] = acc[n] + add;
    }
}

// ---------------- edge kernel: h = relu(A[i]+B[j])@W2 + b2 via f16 MFMA ----------------
// biased-positive uint atomic max into agg (stores h + 256, always > 0)
__global__ __launch_bounds__(256, 2) void k_edge(const float* __restrict__ A,
                                                 const float* __restrict__ Bm,
                                                 const int* __restrict__ esrc,
                                                 const int* __restrict__ edst,
                                                 const float* __restrict__ W2,
                                                 const float* __restrict__ b2,
                                                 unsigned* __restrict__ agg,
                                                 int n_edges) {
    __shared__ __fp16 w2t[OUT_C * RT_PITCH];        // W2^T as f16 [n][k], 34.8 KB
    __shared__ __fp16 rt[WAVES * EPW * RT_PITCH];   // r rows f16 [wave][e][k], 34.8 KB
    __shared__ int dst_lds[WAVES][EPW];

    int t = threadIdx.x;
    int lane = t & 63;
    int wv = __builtin_amdgcn_readfirstlane(t >> 6);
    int mrow = lane & 15;      // MFMA row/col within tile
    int kgrp = lane >> 4;      // MFMA k-group (0..3)

    // stage W2 -> w2t (f16, transposed): idx = kp*128 + n  (coalesced global reads)
    for (int idx = t; idx < 64 * 128; idx += 256) {
        int kp = idx >> 7, n = idx & 127;
        float w0 = W2[(size_t)(2 * kp) * OUT_C + n];
        float w1 = W2[(size_t)(2 * kp + 1) * OUT_C + n];
        f16x2 p = __builtin_amdgcn_cvt_pkrtz(w0, w1);
        *(f16x2*)&w2t[n * RT_PITCH + 2 * kp] = p;
    }
    // per-lane output bias (+BIAS_OFF folded)
    float b2r[8];
#pragma unroll
    for (int nt = 0; nt < 8; nt++) b2r[nt] = b2[nt * 16 + mrow] + BIAS_OFF;
    __syncthreads();   // only barrier: w2t staged cross-wave

    __fp16* rtw = &rt[wv * EPW * RT_PITCH];

    for (int gbase = blockIdx.x * EPB; gbase < n_edges; gbase += gridDim.x * EPB) {
        int ebase = gbase + wv * EPW;
        // lanes 0-31 load src ids, lanes 32-63 load dst ids (clamped)
        int li = lane & 31;
        int eidx = min(ebase + li, n_edges - 1);
        int v_id = (lane < 32) ? esrc[eidx] : edst[eidx];
        if (lane >= 32) dst_lds[wv][li] = v_id;

        // phase 1: gather A[i], B[j]; r = relu(A+B); pack f16 -> per-wave LDS rows
#pragma unroll
        for (int eg = 0; eg < EPW; eg += 8) {
            float2 av[8], bv[8];
#pragma unroll
            for (int e = 0; e < 8; e++) {
                int jj = __builtin_amdgcn_readlane(v_id, eg + e);        // src
                int ii = __builtin_amdgcn_readlane(v_id, 32 + eg + e);   // dst
                av[e] = *(const float2*)&A[(size_t)ii * OUT_C + 2 * lane];
                bv[e] = *(const float2*)&Bm[(size_t)jj * OUT_C + 2 * lane];
            }
#pragma unroll
            for (int e = 0; e < 8; e++) {
                float r0 = fmaxf(av[e].x + bv[e].x, 0.0f);
                float r1 = fmaxf(av[e].y + bv[e].y, 0.0f);
                f16x2 p = __builtin_amdgcn_cvt_pkrtz(r0, r1);
                *(f16x2*)&rtw[(eg + e) * RT_PITCH + 2 * lane] = p;
            }
        }
        // no __syncthreads: rt rows are wave-private (lgkmcnt orders RAW)

        // phase 2: [32 x 128] @ [128 x 128] via 16x16x32 f16 MFMA
        f32x4 acc[2][8];
#pragma unroll
        for (int mt = 0; mt < 2; mt++)
#pragma unroll
            for (int nt = 0; nt < 8; nt++) acc[mt][nt] = (f32x4){0.f, 0.f, 0.f, 0.f};
#pragma unroll
        for (int kk = 0; kk < 4; kk++) {
            int k0 = kk * 32 + kgrp * 8;
            f16x8 a0 = *(f16x8*)&rtw[mrow * RT_PITCH + k0];
            f16x8 a1 = *(f16x8*)&rtw[(16 + mrow) * RT_PITCH + k0];
#pragma unroll
            for (int nt = 0; nt < 8; nt++) {
                f16x8 bf = *(f16x8*)&w2t[(nt * 16 + mrow) * RT_PITCH + k0];
                acc[0][nt] = __builtin_amdgcn_mfma_f32_16x16x32_f16(a0, bf, acc[0][nt], 0, 0, 0);
                acc[1][nt] = __builtin_amdgcn_mfma_f32_16x16x32_f16(a1, bf, acc[1][nt], 0, 0, 0);
            }
        }

        // phase 3: biased uint atomic max. D layout: col = lane&15, row = kgrp*4+reg
#pragma unroll
        for (int mt = 0; mt < 2; mt++) {
#pragma unroll
            for (int reg = 0; reg < 4; reg++) {
                int el = mt * 16 + kgrp * 4 + reg;     // local edge row
                int dsti = dst_lds[wv][el];
                bool valid = (ebase + el) < n_edges;
#pragma unroll
                for (int nt = 0; nt < 8; nt++) {
                    float val = acc[mt][nt][reg] + b2r[nt];
                    if (valid)
                        atomicMax(&agg[(size_t)dsti * OUT_C + nt * 16 + mrow],
                                  __float_as_uint(val));
                }
            }
        }
    }
}

// ---------------- stats: decode bias/sentinel, accumulate sum/sumsq ----------------
__global__ __launch_bounds__(256) void k_stats(float* __restrict__ agg, int n_nodes,
                                               float* __restrict__ gsum,
                                               float* __restrict__ gsumsq) {
    __shared__ float red[256];
    unsigned* uagg = (unsigned*)agg;
    int t = threadIdx.x;
    int c = t & 127, h = t >> 7;
    float s = 0.0f, s2 = 0.0f;
    for (int row = blockIdx.x * 2 + h; row < n_nodes; row += gridDim.x * 2) {
        size_t idx = (size_t)row * OUT_C + c;
        unsigned u = uagg[idx];
        float v = (u == 0u) ? 0.0f : (__uint_as_float(u) - BIAS_OFF);
        agg[idx] = v;
        s += v;
        s2 += v * v;
    }
    red[t] = s;
    __syncthreads();
    if (h == 0) atomicAdd(&gsum[c], s + red[t + 128]);
    __syncthreads();
    red[t] = s2;
    __syncthreads();
    if (h == 0) atomicAdd(&gsumsq[c], s2 + red[t + 128]);
}

// ---------------- finalize: scale/shift from stats ----------------
__global__ __launch_bounds__(128) void k_finalize(const float* __restrict__ gsum,
                                                  const float* __restrict__ gsumsq,
                                                  const float* __restrict__ gamma,
                                                  const float* __restrict__ beta,
                                                  float* __restrict__ scale,
                                                  float* __restrict__ shift,
                                                  int n_nodes) {
    int c = threadIdx.x;
    if (c < OUT_C) {
        float inv_n = 1.0f / (float)n_nodes;
        float mean = gsum[c] * inv_n;
        float var = fmaxf(gsumsq[c] * inv_n - mean * mean, 0.0f);
        float sc = gamma[c] * rsqrtf(var + BN_EPS);
        scale[c] = sc;
        shift[c] = beta[c] - mean * sc;
    }
}

// ---------------- normalize in place ----------------
__global__ __launch_bounds__(256) void k_norm(float* __restrict__ out,
                                              const float* __restrict__ scale,
                                              const float* __restrict__ shift,
                                              int n_vec) {
    int idx = blockIdx.x * blockDim.x + threadIdx.x;
    int stride = gridDim.x * blockDim.x;
    for (int i = idx; i < n_vec; i += stride) {
        float4 v = ((const float4*)out)[i];
        int c = (i * 4) & 127;
        float4 sc = *(const float4*)&scale[c];
        float4 sh = *(const float4*)&shift[c];
        v.x = fmaf(v.x, sc.x, sh.x);
        v.y = fmaf(v.y, sc.y, sh.y);
        v.z = fmaf(v.z, sc.z, sh.z);
        v.w = fmaf(v.w, sc.w, sh.w);
        ((float4*)out)[i] = v;
    }
}

extern "C" void kernel_launch(void* const* d_in, const int* in_sizes, int n_in,
                              void* d_out, int out_size, void* d_ws, size_t ws_size,
                              hipStream_t stream) {
    const float* x     = (const float*)d_in[0];
    const int*   ei    = (const int*)d_in[1];
    const float* W1    = (const float*)d_in[2];
    const float* b1    = (const float*)d_in[3];
    const float* W2    = (const float*)d_in[4];
    const float* b2    = (const float*)d_in[5];
    const float* gamma = (const float*)d_in[6];
    const float* beta  = (const float*)d_in[7];

    int n_nodes = in_sizes[0] / IN_C;
    int n_edges = in_sizes[1] / 2;
    const int* esrc = ei;             // edge_index[0] = source j
    const int* edst = ei + n_edges;   // edge_index[1] = target i

    float* out = (float*)d_out;
    float* A   = (float*)d_ws;
    float* Bm  = A + (size_t)n_nodes * OUT_C;
    float* stats = Bm + (size_t)n_nodes * OUT_C;
    float* gsum   = stats;
    float* gsumsq = stats + 128;
    float* scale  = stats + 256;
    float* shift  = stats + 384;

    int n_elem = n_nodes * OUT_C;

    k_init<<<2048, 256, 0, stream>>>(out, n_elem, stats);
    k_node<<<2048, 256, 0, stream>>>(x, W1, b1, A, Bm, n_nodes);
    k_edge<<<512, 256, 0, stream>>>(A, Bm, esrc, edst, W2, b2,
                                    (unsigned*)out, n_edges);
    k_stats<<<1024, 256, 0, stream>>>(out, n_nodes, gsum, gsumsq);
    k_finalize<<<1, 128, 0, stream>>>(gsum, gsumsq, gamma, beta, scale, shift, n_nodes);
    k_norm<<<2048, 256, 0, stream>>>(out, scale, shift, n_elem / 4);
}